// Round 12
// baseline (187.882 us; speedup 1.0000x reference)
//
#include <hip/hip_runtime.h>

typedef _Float16 half4 __attribute__((ext_vector_type(4)));
typedef _Float16 half8 __attribute__((ext_vector_type(8)));
typedef float floatx4 __attribute__((ext_vector_type(4)));

#define U_RESV 400
#define A_RESV 50

#define UHALVES (U_RESV * U_RESV * 8)   // 1,280,000
#define AHALVES (A_RESV * A_RESV * 8)   // 20,000
#define WOFF    (UHALVES + 2 * AHALVES) // weights offset (halves)
// W0 32x28 (cols>=24 zero) | W1 32x36 | W2 32x36 | W3 16x36 (rows>=3 zero)
#define W0OFF   0
#define W1OFF   896
#define W2OFF   2048
#define W3OFF   3200
#define WTOT    3776                    // halves; 7552 B = 472 x 16 B

__device__ __forceinline__ float clamp01(float x) { return fminf(fmaxf(x, 0.0f), 1.0f); }

__device__ __forceinline__ floatx4 mfma16(half4 a, half4 b, floatx4 c) {
    return __builtin_amdgcn_mfma_f32_16x16x16f16(a, b, c, 0, 0, 0);
}
__device__ __forceinline__ half4 zero4() {
    half4 h; h[0] = h[1] = h[2] = h[3] = (_Float16)0.f; return h;
}
__device__ __forceinline__ half4 relu4(half4 v) {
#if __has_builtin(__builtin_elementwise_max)
    return __builtin_elementwise_max(v, zero4());
#else
    half4 r;
#pragma unroll
    for (int i = 0; i < 4; ++i) r[i] = v[i] > (_Float16)0.f ? v[i] : (_Float16)0.f;
    return r;
#endif
}

__device__ __forceinline__ void cvt_chunk(const float* __restrict__ src,
                                          _Float16* __restrict__ dst, int i) {
    float4 a = *(const float4*)(src + (size_t)i * 8);
    float4 b = *(const float4*)(src + (size_t)i * 8 + 4);
    half8 h;
    h[0] = (_Float16)a.x; h[1] = (_Float16)a.y; h[2] = (_Float16)a.z; h[3] = (_Float16)a.w;
    h[4] = (_Float16)b.x; h[5] = (_Float16)b.y; h[6] = (_Float16)b.z; h[7] = (_Float16)b.w;
    *(half8*)(dst + (size_t)i * 8) = h;
}

__device__ __forceinline__ void wblob_fill(const float* __restrict__ W0,
                                           const float* __restrict__ W1,
                                           const float* __restrict__ W2,
                                           const float* __restrict__ W3,
                                           _Float16* __restrict__ w, int tid, int nthr) {
    for (int i = tid; i < WTOT; i += nthr) {
        float v;
        if (i < W1OFF) {
            int r = i / 28, c = i - r * 28;
            v = (c < 24) ? W0[r * 24 + c] : 0.f;
        } else if (i < W2OFF) {
            int j = i - W1OFF, r = j / 36, c = j - r * 36;
            v = (c < 32) ? W1[r * 32 + c] : 0.f;
        } else if (i < W3OFF) {
            int j = i - W2OFF, r = j / 36, c = j - r * 36;
            v = (c < 32) ? W2[r * 32 + c] : 0.f;
        } else {
            int j = i - W3OFF, r = j / 36, c = j - r * 36;
            v = (r < 3 && c < 32) ? W3[r * 32 + c] : 0.f;
        }
        w[i] = (_Float16)v;
    }
}

// ---- prep: all planes + weights -> f16 blob in ws ----
__global__ __launch_bounds__(256) void pconv_kernel(
    const float* __restrict__ u_plane, const float* __restrict__ h_plane,
    const float* __restrict__ d_plane, const float* __restrict__ W0,
    const float* __restrict__ W1, const float* __restrict__ W2,
    const float* __restrict__ W3, _Float16* __restrict__ dst) {
    const int gid = blockIdx.x * 256 + threadIdx.x;
    const int gsz = gridDim.x * 256;
    for (int i = gid; i < UHALVES / 8; i += gsz) cvt_chunk(u_plane, dst, i);
    for (int i = gid; i < AHALVES / 8; i += gsz) cvt_chunk(h_plane, dst + UHALVES, i);
    for (int i = gid; i < AHALVES / 8; i += gsz) cvt_chunk(d_plane, dst + UHALVES + AHALVES, i);
    if (blockIdx.x == 0) wblob_fill(W0, W1, W2, W3, dst + WOFF, threadIdx.x, 256);
}

__global__ __launch_bounds__(256) void wprep_kernel(
    const float* __restrict__ W0, const float* __restrict__ W1,
    const float* __restrict__ W2, const float* __restrict__ W3,
    _Float16* __restrict__ wdst) {
    wblob_fill(W0, W1, W2, W3, wdst, threadIdx.x, 256);
}

// R12: 1024-thread blocks -> LDS 64.9 KB -> exactly 2 blocks/CU = 32 waves
// (100% occupancy); per-point code identical to R11 (verified maps/arith).
// 1 thread/point, 12 x 16B half8 texel loads, sched_barrier pins all in
// flight; x-loads issued FIRST (critical path), staging after; lgkm-only
// s_barrier keeps texels in flight across the weight handoff.
// MFMA maps (verified R4..R11, 16x16x16 f16):
//   A: lane 16q+c holds A[row=c][k=4q+e];  B: lane 16q+c holds B[k=4q+e][col=c]
//   D: lane 16q+c reg r holds D[row=4q+r][col=c]
// Chain identity: D reg r == next-layer B elem e. MLP chains in registers;
// wave owns 64 points (j-tiles 0..3).

template <bool F16P>
__global__ __launch_bounds__(1024, 8) void tpmlp_kernel(
    const float* __restrict__ x,
    const void* __restrict__ u_tex,
    const void* __restrict__ h_tex,
    const void* __restrict__ d_tex,
    const _Float16* __restrict__ wsw,
    float* __restrict__ out) {
    const int tid  = threadIdx.x;
    const int lane = tid & 63;
    const int wv   = tid >> 6;
    const int q    = lane >> 4;
    const int c15  = lane & 15;

    __shared__ __align__(16) _Float16 fl[1024 * 28];  // feat: 1024 pts x 28 (56 B stride)
    __shared__ __align__(16) _Float16 wl[WTOT];

    // ---- 1. x loads (critical path -> first) ----
    const size_t P = (size_t)blockIdx.x * 1024 + tid;
    const float2* xp = (const float2*)(x + P * 6);
    float2 p01v = xp[0], p23v = xp[1], p45v = xp[2];

    // ---- 2. weight staging loads (1 chunk/thread, 472 total) ----
    uint4 w_a;
    if (tid < 472) w_a = ((const uint4*)wsw)[tid];

    // ---- 3. gather addresses (once per point) ----
    int oU0, oU1, oU2, oU3;  float uw00, uw10, uw01, uw11;
    {
        float u = clamp01(p01v.x) * (float)(U_RESV - 1);
        float v = clamp01(p01v.y) * (float)(U_RESV - 1);
        float x0f = floorf(u), y0f = floorf(v);
        int x0 = (int)x0f, y0 = (int)y0f;
        int x1 = min(x0 + 1, U_RESV - 1), y1 = min(y0 + 1, U_RESV - 1);
        float ur = u - x0f, vr = v - y0f;
        uw00 = (1.0f - ur) * (1.0f - vr); uw10 = ur * (1.0f - vr);
        uw01 = (1.0f - ur) * vr;          uw11 = ur * vr;
        oU0 = (y0 * U_RESV + x0) * 8;
        oU1 = (y0 * U_RESV + x1) * 8;
        oU2 = (y1 * U_RESV + x0) * 8;
        oU3 = (y1 * U_RESV + x1) * 8;
    }
    int oH0, oH1, oH2, oH3;  float hw00, hw10, hw01, hw11;
    {
        float uu = p23v.y, vv = p23v.x;
        float uf = uu - floorf(uu);
        float u = uf * (float)A_RESV;                 // in [0,50)
        float v = clamp01(vv) * (float)(A_RESV - 1);
        float x0f = floorf(u), y0f = floorf(v);
        int x0 = (int)x0f;
        int x1 = x0 + 1; if (x1 == A_RESV) x1 = 0;
        int y0 = (int)y0f;
        int y1 = min(y0 + 1, A_RESV - 1);
        float ur = u - x0f, vr = v - y0f;
        hw00 = (1.0f - ur) * (1.0f - vr); hw10 = ur * (1.0f - vr);
        hw01 = (1.0f - ur) * vr;          hw11 = ur * vr;
        oH0 = (y0 * A_RESV + x0) * 8;
        oH1 = (y0 * A_RESV + x1) * 8;
        oH2 = (y1 * A_RESV + x0) * 8;
        oH3 = (y1 * A_RESV + x1) * 8;
    }
    int oD0, oD1, oD2, oD3;  float dw00, dw10, dw01, dw11;
    {
        float uu = p45v.y, vv = p45v.x;
        float uf = uu - floorf(uu);
        float u = uf * (float)A_RESV;
        float v = clamp01(vv) * (float)(A_RESV - 1);
        float x0f = floorf(u), y0f = floorf(v);
        int x0 = (int)x0f;
        int x1 = x0 + 1; if (x1 == A_RESV) x1 = 0;
        int y0 = (int)y0f;
        int y1 = min(y0 + 1, A_RESV - 1);
        float ur = u - x0f, vr = v - y0f;
        dw00 = (1.0f - ur) * (1.0f - vr); dw10 = ur * (1.0f - vr);
        dw01 = (1.0f - ur) * vr;          dw11 = ur * vr;
        oD0 = (y0 * A_RESV + x0) * 8;
        oD1 = (y0 * A_RESV + x1) * 8;
        oD2 = (y1 * A_RESV + x0) * 8;
        oD3 = (y1 * A_RESV + x1) * 8;
    }

    // ---- 4. issue ALL 12 texel loads (16 B each) ----
    half8 gU0, gU1, gU2, gU3, gH0, gH1, gH2, gH3, gD0, gD1, gD2, gD3;
    float4 sU0, sU1, sU2, sU3, sH0, sH1, sH2, sH3, sD0, sD1, sD2, sD3;
    float4 rU0, rU1, rU2, rU3, rH0, rH1, rH2, rH3, rD0, rD1, rD2, rD3;
    if constexpr (F16P) {
        const _Float16* up = (const _Float16*)u_tex;
        const _Float16* hp = (const _Float16*)h_tex;
        const _Float16* dp = (const _Float16*)d_tex;
        gU0 = *(const half8*)(up + oU0);
        gU1 = *(const half8*)(up + oU1);
        gU2 = *(const half8*)(up + oU2);
        gU3 = *(const half8*)(up + oU3);
        gH0 = *(const half8*)(hp + oH0);
        gH1 = *(const half8*)(hp + oH1);
        gH2 = *(const half8*)(hp + oH2);
        gH3 = *(const half8*)(hp + oH3);
        gD0 = *(const half8*)(dp + oD0);
        gD1 = *(const half8*)(dp + oD1);
        gD2 = *(const half8*)(dp + oD2);
        gD3 = *(const half8*)(dp + oD3);
    } else {
        const float* up = (const float*)u_tex;
        const float* hp = (const float*)h_tex;
        const float* dp = (const float*)d_tex;
        sU0 = *(const float4*)(up + oU0); rU0 = *(const float4*)(up + oU0 + 4);
        sU1 = *(const float4*)(up + oU1); rU1 = *(const float4*)(up + oU1 + 4);
        sU2 = *(const float4*)(up + oU2); rU2 = *(const float4*)(up + oU2 + 4);
        sU3 = *(const float4*)(up + oU3); rU3 = *(const float4*)(up + oU3 + 4);
        sH0 = *(const float4*)(hp + oH0); rH0 = *(const float4*)(hp + oH0 + 4);
        sH1 = *(const float4*)(hp + oH1); rH1 = *(const float4*)(hp + oH1 + 4);
        sH2 = *(const float4*)(hp + oH2); rH2 = *(const float4*)(hp + oH2 + 4);
        sH3 = *(const float4*)(hp + oH3); rH3 = *(const float4*)(hp + oH3 + 4);
        sD0 = *(const float4*)(dp + oD0); rD0 = *(const float4*)(dp + oD0 + 4);
        sD1 = *(const float4*)(dp + oD1); rD1 = *(const float4*)(dp + oD1 + 4);
        sD2 = *(const float4*)(dp + oD2); rD2 = *(const float4*)(dp + oD2 + 4);
        sD3 = *(const float4*)(dp + oD3); rD3 = *(const float4*)(dp + oD3 + 4);
    }
    // Pin: all loads issued before anything below; results all live.
    __builtin_amdgcn_sched_barrier(0);

    // ---- 5. weight LDS writes ----
    if (tid < 472) ((uint4*)wl)[tid] = w_a;
    // ---- 6. lgkmcnt-only barrier: texel loads stay in flight ----
    asm volatile("s_waitcnt lgkmcnt(0)" ::: "memory");
    __builtin_amdgcn_s_barrier();

    // ---- 7. weighted sums, all 8 channels (exact per-channel FMA order) ----
    float fU[8], fH[8], fD[8];
    if constexpr (F16P) {
#pragma unroll
        for (int i = 0; i < 8; ++i) {
            float r = (float)gU0[i] * uw00;
            r = fmaf((float)gU1[i], uw10, r);
            r = fmaf((float)gU2[i], uw01, r);
            r = fmaf((float)gU3[i], uw11, r);
            fU[i] = r;
        }
#pragma unroll
        for (int i = 0; i < 8; ++i) {
            float r = (float)gH0[i] * hw00;
            r = fmaf((float)gH1[i], hw10, r);
            r = fmaf((float)gH2[i], hw01, r);
            r = fmaf((float)gH3[i], hw11, r);
            fH[i] = r;
        }
#pragma unroll
        for (int i = 0; i < 8; ++i) {
            float r = (float)gD0[i] * dw00;
            r = fmaf((float)gD1[i], dw10, r);
            r = fmaf((float)gD2[i], dw01, r);
            r = fmaf((float)gD3[i], dw11, r);
            fD[i] = r;
        }
    } else {
        const float* a;
        const float* b;
        const float* c;
        const float* d;
#pragma unroll
        for (int i = 0; i < 8; ++i) {
            a = i < 4 ? (const float*)&sU0 : (const float*)&rU0;
            b = i < 4 ? (const float*)&sU1 : (const float*)&rU1;
            c = i < 4 ? (const float*)&sU2 : (const float*)&rU2;
            d = i < 4 ? (const float*)&sU3 : (const float*)&rU3;
            int k = i & 3;
            float r = a[k] * uw00;
            r = fmaf(b[k], uw10, r);
            r = fmaf(c[k], uw01, r);
            r = fmaf(d[k], uw11, r);
            fU[i] = r;
        }
#pragma unroll
        for (int i = 0; i < 8; ++i) {
            a = i < 4 ? (const float*)&sH0 : (const float*)&rH0;
            b = i < 4 ? (const float*)&sH1 : (const float*)&rH1;
            c = i < 4 ? (const float*)&sH2 : (const float*)&rH2;
            d = i < 4 ? (const float*)&sH3 : (const float*)&rH3;
            int k = i & 3;
            float r = a[k] * hw00;
            r = fmaf(b[k], hw10, r);
            r = fmaf(c[k], hw01, r);
            r = fmaf(d[k], hw11, r);
            fH[i] = r;
        }
#pragma unroll
        for (int i = 0; i < 8; ++i) {
            a = i < 4 ? (const float*)&sD0 : (const float*)&rD0;
            b = i < 4 ? (const float*)&sD1 : (const float*)&rD1;
            c = i < 4 ? (const float*)&sD2 : (const float*)&rD2;
            d = i < 4 ? (const float*)&sD3 : (const float*)&rD3;
            int k = i & 3;
            float r = a[k] * dw00;
            r = fmaf(b[k], dw10, r);
            r = fmaf(c[k], dw01, r);
            r = fmaf(d[k], dw11, r);
            fD[i] = r;
        }
    }

    // ---- 8. feat -> f16 -> LDS (row = my point) ----
    {
        _Float16* row = fl + tid * 28;
        half8 hU, hH, hD;
#pragma unroll
        for (int i = 0; i < 8; ++i) {
            hU[i] = (_Float16)fU[i];
            hH[i] = (_Float16)fH[i];
            hD[i] = (_Float16)fD[i];
        }
        *(half8*)(row)      = hU;   // ch 0-7
        *(half8*)(row + 8)  = hH;   // ch 8-15
        *(half8*)(row + 16) = hD;   // ch 16-23
    }
    // wave-local handoff (feat rows wv*64..+63 written/read by wave wv only)
    asm volatile("s_waitcnt lgkmcnt(0)" ::: "memory");
    __builtin_amdgcn_sched_barrier(0);

    // ---- 9. MLP: wave owns 64 points, j-tiles {0..3} ----
    floatx4 zf; zf[0] = 0.f; zf[1] = 0.f; zf[2] = 0.f; zf[3] = 0.f;
    const _Float16* wb = fl + (size_t)wv * 64 * 28;
    const _Float16* w0l = wl + W0OFF;
    const _Float16* w1l = wl + W1OFF;
    const _Float16* w2l = wl + W2OFF;
    const _Float16* w3l = wl + W3OFF;

    half4 b0[4], b1[4];
#pragma unroll
    for (int j = 0; j < 4; ++j) {
        const _Float16* r = wb + (size_t)(j * 16 + c15) * 28;
        b0[j] = *(const half4*)(r + q * 4);
        b1[j] = (q < 2) ? *(const half4*)(r + 16 + q * 4) : zero4();
    }

    floatx4 cc[2][4];
    // layer 0 (K=24: k-half1 zero for q>=2 on both operands; W0 stride 28)
#pragma unroll
    for (int m = 0; m < 2; ++m) {
        half4 a0 = *(const half4*)(w0l + (size_t)(16 * m + c15) * 28 + q * 4);
        half4 a1 = (q < 2) ? *(const half4*)(w0l + (size_t)(16 * m + c15) * 28 + 16 + q * 4) : zero4();
#pragma unroll
        for (int j = 0; j < 4; ++j)
            cc[m][j] = mfma16(a1, b1[j], mfma16(a0, b0[j], zf));
    }
#pragma unroll
    for (int j = 0; j < 4; ++j) {
#pragma unroll
        for (int e = 0; e < 4; ++e) {
            b0[j][e] = (_Float16)cc[0][j][e];
            b1[j][e] = (_Float16)cc[1][j][e];
        }
        b0[j] = relu4(b0[j]);
        b1[j] = relu4(b1[j]);
    }

    // layer 1
#pragma unroll
    for (int m = 0; m < 2; ++m) {
        half4 a0 = *(const half4*)(w1l + (size_t)(16 * m + c15) * 36 + q * 4);
        half4 a1 = *(const half4*)(w1l + (size_t)(16 * m + c15) * 36 + 16 + q * 4);
#pragma unroll
        for (int j = 0; j < 4; ++j)
            cc[m][j] = mfma16(a1, b1[j], mfma16(a0, b0[j], zf));
    }
#pragma unroll
    for (int j = 0; j < 4; ++j) {
#pragma unroll
        for (int e = 0; e < 4; ++e) {
            b0[j][e] = (_Float16)cc[0][j][e];
            b1[j][e] = (_Float16)cc[1][j][e];
        }
        b0[j] = relu4(b0[j]);
        b1[j] = relu4(b1[j]);
    }

    // layer 2
#pragma unroll
    for (int m = 0; m < 2; ++m) {
        half4 a0 = *(const half4*)(w2l + (size_t)(16 * m + c15) * 36 + q * 4);
        half4 a1 = *(const half4*)(w2l + (size_t)(16 * m + c15) * 36 + 16 + q * 4);
#pragma unroll
        for (int j = 0; j < 4; ++j)
            cc[m][j] = mfma16(a1, b1[j], mfma16(a0, b0[j], zf));
    }
#pragma unroll
    for (int j = 0; j < 4; ++j) {
#pragma unroll
        for (int e = 0; e < 4; ++e) {
            b0[j][e] = (_Float16)cc[0][j][e];
            b1[j][e] = (_Float16)cc[1][j][e];
        }
        b0[j] = relu4(b0[j]);
        b1[j] = relu4(b1[j]);
    }

    // layer 3 (rows 0-2 valid; w3l rows 3-15 zero)
    floatx4 c3[4];
    {
        half4 a0 = *(const half4*)(w3l + (size_t)c15 * 36 + q * 4);
        half4 a1 = *(const half4*)(w3l + (size_t)c15 * 36 + 16 + q * 4);
#pragma unroll
        for (int j = 0; j < 4; ++j)
            c3[j] = mfma16(a1, b1[j], mfma16(a0, b0[j], zf));
    }

    if (lane < 16) {
        const size_t base = (size_t)blockIdx.x * 1024 + (size_t)wv * 64;
#pragma unroll
        for (int j = 0; j < 4; ++j) {
            size_t p = base + (size_t)j * 16 + lane;
            float* o = out + p * 3;
            o[0] = c3[j][0];
            o[1] = c3[j][1];
            o[2] = c3[j][2];
        }
    }
}

extern "C" void kernel_launch(void* const* d_in, const int* in_sizes, int n_in,
                              void* d_out, int out_size, void* d_ws, size_t ws_size,
                              hipStream_t stream) {
    const float* x       = (const float*)d_in[0];
    const float* u_plane = (const float*)d_in[1];
    const float* h_plane = (const float*)d_in[2];
    const float* d_plane = (const float*)d_in[3];
    const float* W0      = (const float*)d_in[4];
    const float* W1      = (const float*)d_in[5];
    const float* W2      = (const float*)d_in[6];
    const float* W3      = (const float*)d_in[7];
    float* out = (float*)d_out;
    _Float16* wsw = (_Float16*)d_ws;

    int n = in_sizes[0] / 6;          // 2^21
    int grid = n / 1024;              // 1024 points per block, 1 thread/point

    const size_t need = ((size_t)WOFF + WTOT) * 2;
    if (ws_size >= need) {
        pconv_kernel<<<648, 256, 0, stream>>>(u_plane, h_plane, d_plane,
                                              W0, W1, W2, W3, wsw);
        tpmlp_kernel<true><<<grid, 1024, 0, stream>>>(
            x, (const void*)wsw, (const void*)(wsw + UHALVES),
            (const void*)(wsw + UHALVES + AHALVES), wsw + WOFF, out);
    } else {
        wprep_kernel<<<1, 256, 0, stream>>>(W0, W1, W2, W3, wsw);
        tpmlp_kernel<false><<<grid, 1024, 0, stream>>>(
            x, (const void*)u_plane, (const void*)h_plane, (const void*)d_plane,
            wsw, out);
    }
}

// Round 13
// 72.682 us; speedup vs baseline: 2.5850x; 2.5850x over previous
//
#include <hip/hip_runtime.h>

typedef _Float16 half4 __attribute__((ext_vector_type(4)));
typedef _Float16 half8 __attribute__((ext_vector_type(8)));
typedef float floatx4 __attribute__((ext_vector_type(4)));

#define U_RESV 400
#define A_RESV 50

#define UHALVES (U_RESV * U_RESV * 8)   // 1,280,000
#define AHALVES (A_RESV * A_RESV * 8)   // 20,000
#define WOFF    (UHALVES + 2 * AHALVES) // weights offset (halves)
// W0 32x28 (cols>=24 zero) | W1 32x36 | W2 32x36 | W3 16x36 (rows>=3 zero)
#define W0OFF   0
#define W1OFF   896
#define W2OFF   2048
#define W3OFF   3200
#define WTOT    3776                    // halves; 7552 B = 472 x 16 B

__device__ __forceinline__ float clamp01(float x) { return fminf(fmaxf(x, 0.0f), 1.0f); }

__device__ __forceinline__ floatx4 mfma16(half4 a, half4 b, floatx4 c) {
    return __builtin_amdgcn_mfma_f32_16x16x16f16(a, b, c, 0, 0, 0);
}
__device__ __forceinline__ half4 zero4() {
    half4 h; h[0] = h[1] = h[2] = h[3] = (_Float16)0.f; return h;
}
__device__ __forceinline__ half4 relu4(half4 v) {
#if __has_builtin(__builtin_elementwise_max)
    return __builtin_elementwise_max(v, zero4());
#else
    half4 r;
#pragma unroll
    for (int i = 0; i < 4; ++i) r[i] = v[i] > (_Float16)0.f ? v[i] : (_Float16)0.f;
    return r;
#endif
}

__device__ __forceinline__ void cvt_chunk(const float* __restrict__ src,
                                          _Float16* __restrict__ dst, int i) {
    float4 a = *(const float4*)(src + (size_t)i * 8);
    float4 b = *(const float4*)(src + (size_t)i * 8 + 4);
    half8 h;
    h[0] = (_Float16)a.x; h[1] = (_Float16)a.y; h[2] = (_Float16)a.z; h[3] = (_Float16)a.w;
    h[4] = (_Float16)b.x; h[5] = (_Float16)b.y; h[6] = (_Float16)b.z; h[7] = (_Float16)b.w;
    *(half8*)(dst + (size_t)i * 8) = h;
}

__device__ __forceinline__ void wblob_fill(const float* __restrict__ W0,
                                           const float* __restrict__ W1,
                                           const float* __restrict__ W2,
                                           const float* __restrict__ W3,
                                           _Float16* __restrict__ w, int tid, int nthr) {
    for (int i = tid; i < WTOT; i += nthr) {
        float v;
        if (i < W1OFF) {
            int r = i / 28, c = i - r * 28;
            v = (c < 24) ? W0[r * 24 + c] : 0.f;
        } else if (i < W2OFF) {
            int j = i - W1OFF, r = j / 36, c = j - r * 36;
            v = (c < 32) ? W1[r * 32 + c] : 0.f;
        } else if (i < W3OFF) {
            int j = i - W2OFF, r = j / 36, c = j - r * 36;
            v = (c < 32) ? W2[r * 32 + c] : 0.f;
        } else {
            int j = i - W3OFF, r = j / 36, c = j - r * 36;
            v = (r < 3 && c < 32) ? W3[r * 32 + c] : 0.f;
        }
        w[i] = (_Float16)v;
    }
}

// ---- prep: all planes + weights -> f16 blob in ws ----
__global__ __launch_bounds__(256) void pconv_kernel(
    const float* __restrict__ u_plane, const float* __restrict__ h_plane,
    const float* __restrict__ d_plane, const float* __restrict__ W0,
    const float* __restrict__ W1, const float* __restrict__ W2,
    const float* __restrict__ W3, _Float16* __restrict__ dst) {
    const int gid = blockIdx.x * 256 + threadIdx.x;
    const int gsz = gridDim.x * 256;
    for (int i = gid; i < UHALVES / 8; i += gsz) cvt_chunk(u_plane, dst, i);
    for (int i = gid; i < AHALVES / 8; i += gsz) cvt_chunk(h_plane, dst + UHALVES, i);
    for (int i = gid; i < AHALVES / 8; i += gsz) cvt_chunk(d_plane, dst + UHALVES + AHALVES, i);
    if (blockIdx.x == 0) wblob_fill(W0, W1, W2, W3, dst + WOFF, threadIdx.x, 256);
}

__global__ __launch_bounds__(256) void wprep_kernel(
    const float* __restrict__ W0, const float* __restrict__ W1,
    const float* __restrict__ W2, const float* __restrict__ W3,
    _Float16* __restrict__ wdst) {
    wblob_fill(W0, W1, W2, W3, wdst, threadIdx.x, 256);
}

// R13: R11 verbatim, geometry only -> 512-thread blocks, launch_bounds(512,2)
// (VGPR cap 256: NO spill risk — R12's (1024,8) cap=64 spilled texel payloads
// to scratch, WRITE_SIZE 344 MB, 216us). LDS 36.2 KB -> 4 blocks/CU = 32
// waves = 100% occupancy by LDS.
// 1 thread/point, 12 x 16B half8 texel loads, sched_barrier pins all in
// flight; x-loads first (critical path); lgkm-only s_barrier for weights.
// MFMA maps (verified R4..R11, 16x16x16 f16):
//   A: lane 16q+c holds A[row=c][k=4q+e];  B: lane 16q+c holds B[k=4q+e][col=c]
//   D: lane 16q+c reg r holds D[row=4q+r][col=c]
// Chain identity: D reg r == next-layer B elem e. MLP chains in registers;
// wave owns 64 points (j-tiles 0..3).

template <bool F16P>
__global__ __launch_bounds__(512, 2) void tpmlp_kernel(
    const float* __restrict__ x,
    const void* __restrict__ u_tex,
    const void* __restrict__ h_tex,
    const void* __restrict__ d_tex,
    const _Float16* __restrict__ wsw,
    float* __restrict__ out) {
    const int tid  = threadIdx.x;
    const int lane = tid & 63;
    const int wv   = tid >> 6;
    const int q    = lane >> 4;
    const int c15  = lane & 15;

    __shared__ __align__(16) _Float16 fl[512 * 28];   // feat: 512 pts x 28 (56 B stride)
    __shared__ __align__(16) _Float16 wl[WTOT];

    // ---- 1. x loads (critical path -> first) ----
    const size_t P = (size_t)blockIdx.x * 512 + tid;
    const float2* xp = (const float2*)(x + P * 6);
    float2 p01v = xp[0], p23v = xp[1], p45v = xp[2];

    // ---- 2. weight staging loads (472 chunks over 512 threads) ----
    uint4 w_a;
    if (tid < 472) w_a = ((const uint4*)wsw)[tid];

    // ---- 3. gather addresses (once per point) ----
    int oU0, oU1, oU2, oU3;  float uw00, uw10, uw01, uw11;
    {
        float u = clamp01(p01v.x) * (float)(U_RESV - 1);
        float v = clamp01(p01v.y) * (float)(U_RESV - 1);
        float x0f = floorf(u), y0f = floorf(v);
        int x0 = (int)x0f, y0 = (int)y0f;
        int x1 = min(x0 + 1, U_RESV - 1), y1 = min(y0 + 1, U_RESV - 1);
        float ur = u - x0f, vr = v - y0f;
        uw00 = (1.0f - ur) * (1.0f - vr); uw10 = ur * (1.0f - vr);
        uw01 = (1.0f - ur) * vr;          uw11 = ur * vr;
        oU0 = (y0 * U_RESV + x0) * 8;
        oU1 = (y0 * U_RESV + x1) * 8;
        oU2 = (y1 * U_RESV + x0) * 8;
        oU3 = (y1 * U_RESV + x1) * 8;
    }
    int oH0, oH1, oH2, oH3;  float hw00, hw10, hw01, hw11;
    {
        float uu = p23v.y, vv = p23v.x;
        float uf = uu - floorf(uu);
        float u = uf * (float)A_RESV;                 // in [0,50)
        float v = clamp01(vv) * (float)(A_RESV - 1);
        float x0f = floorf(u), y0f = floorf(v);
        int x0 = (int)x0f;
        int x1 = x0 + 1; if (x1 == A_RESV) x1 = 0;
        int y0 = (int)y0f;
        int y1 = min(y0 + 1, A_RESV - 1);
        float ur = u - x0f, vr = v - y0f;
        hw00 = (1.0f - ur) * (1.0f - vr); hw10 = ur * (1.0f - vr);
        hw01 = (1.0f - ur) * vr;          hw11 = ur * vr;
        oH0 = (y0 * A_RESV + x0) * 8;
        oH1 = (y0 * A_RESV + x1) * 8;
        oH2 = (y1 * A_RESV + x0) * 8;
        oH3 = (y1 * A_RESV + x1) * 8;
    }
    int oD0, oD1, oD2, oD3;  float dw00, dw10, dw01, dw11;
    {
        float uu = p45v.y, vv = p45v.x;
        float uf = uu - floorf(uu);
        float u = uf * (float)A_RESV;
        float v = clamp01(vv) * (float)(A_RESV - 1);
        float x0f = floorf(u), y0f = floorf(v);
        int x0 = (int)x0f;
        int x1 = x0 + 1; if (x1 == A_RESV) x1 = 0;
        int y0 = (int)y0f;
        int y1 = min(y0 + 1, A_RESV - 1);
        float ur = u - x0f, vr = v - y0f;
        dw00 = (1.0f - ur) * (1.0f - vr); dw10 = ur * (1.0f - vr);
        dw01 = (1.0f - ur) * vr;          dw11 = ur * vr;
        oD0 = (y0 * A_RESV + x0) * 8;
        oD1 = (y0 * A_RESV + x1) * 8;
        oD2 = (y1 * A_RESV + x0) * 8;
        oD3 = (y1 * A_RESV + x1) * 8;
    }

    // ---- 4. issue ALL 12 texel loads (16 B each) ----
    half8 gU0, gU1, gU2, gU3, gH0, gH1, gH2, gH3, gD0, gD1, gD2, gD3;
    float4 sU0, sU1, sU2, sU3, sH0, sH1, sH2, sH3, sD0, sD1, sD2, sD3;
    float4 rU0, rU1, rU2, rU3, rH0, rH1, rH2, rH3, rD0, rD1, rD2, rD3;
    if constexpr (F16P) {
        const _Float16* up = (const _Float16*)u_tex;
        const _Float16* hp = (const _Float16*)h_tex;
        const _Float16* dp = (const _Float16*)d_tex;
        gU0 = *(const half8*)(up + oU0);
        gU1 = *(const half8*)(up + oU1);
        gU2 = *(const half8*)(up + oU2);
        gU3 = *(const half8*)(up + oU3);
        gH0 = *(const half8*)(hp + oH0);
        gH1 = *(const half8*)(hp + oH1);
        gH2 = *(const half8*)(hp + oH2);
        gH3 = *(const half8*)(hp + oH3);
        gD0 = *(const half8*)(dp + oD0);
        gD1 = *(const half8*)(dp + oD1);
        gD2 = *(const half8*)(dp + oD2);
        gD3 = *(const half8*)(dp + oD3);
    } else {
        const float* up = (const float*)u_tex;
        const float* hp = (const float*)h_tex;
        const float* dp = (const float*)d_tex;
        sU0 = *(const float4*)(up + oU0); rU0 = *(const float4*)(up + oU0 + 4);
        sU1 = *(const float4*)(up + oU1); rU1 = *(const float4*)(up + oU1 + 4);
        sU2 = *(const float4*)(up + oU2); rU2 = *(const float4*)(up + oU2 + 4);
        sU3 = *(const float4*)(up + oU3); rU3 = *(const float4*)(up + oU3 + 4);
        sH0 = *(const float4*)(hp + oH0); rH0 = *(const float4*)(hp + oH0 + 4);
        sH1 = *(const float4*)(hp + oH1); rH1 = *(const float4*)(hp + oH1 + 4);
        sH2 = *(const float4*)(hp + oH2); rH2 = *(const float4*)(hp + oH2 + 4);
        sH3 = *(const float4*)(hp + oH3); rH3 = *(const float4*)(hp + oH3 + 4);
        sD0 = *(const float4*)(dp + oD0); rD0 = *(const float4*)(dp + oD0 + 4);
        sD1 = *(const float4*)(dp + oD1); rD1 = *(const float4*)(dp + oD1 + 4);
        sD2 = *(const float4*)(dp + oD2); rD2 = *(const float4*)(dp + oD2 + 4);
        sD3 = *(const float4*)(dp + oD3); rD3 = *(const float4*)(dp + oD3 + 4);
    }
    // Pin: all loads issued before anything below; results all live.
    __builtin_amdgcn_sched_barrier(0);

    // ---- 5. weight LDS writes ----
    if (tid < 472) ((uint4*)wl)[tid] = w_a;
    // ---- 6. lgkmcnt-only barrier: texel loads stay in flight ----
    asm volatile("s_waitcnt lgkmcnt(0)" ::: "memory");
    __builtin_amdgcn_s_barrier();

    // ---- 7. weighted sums, all 8 channels (exact per-channel FMA order) ----
    float fU[8], fH[8], fD[8];
    if constexpr (F16P) {
#pragma unroll
        for (int i = 0; i < 8; ++i) {
            float r = (float)gU0[i] * uw00;
            r = fmaf((float)gU1[i], uw10, r);
            r = fmaf((float)gU2[i], uw01, r);
            r = fmaf((float)gU3[i], uw11, r);
            fU[i] = r;
        }
#pragma unroll
        for (int i = 0; i < 8; ++i) {
            float r = (float)gH0[i] * hw00;
            r = fmaf((float)gH1[i], hw10, r);
            r = fmaf((float)gH2[i], hw01, r);
            r = fmaf((float)gH3[i], hw11, r);
            fH[i] = r;
        }
#pragma unroll
        for (int i = 0; i < 8; ++i) {
            float r = (float)gD0[i] * dw00;
            r = fmaf((float)gD1[i], dw10, r);
            r = fmaf((float)gD2[i], dw01, r);
            r = fmaf((float)gD3[i], dw11, r);
            fD[i] = r;
        }
    } else {
        const float* a;
        const float* b;
        const float* c;
        const float* d;
#pragma unroll
        for (int i = 0; i < 8; ++i) {
            a = i < 4 ? (const float*)&sU0 : (const float*)&rU0;
            b = i < 4 ? (const float*)&sU1 : (const float*)&rU1;
            c = i < 4 ? (const float*)&sU2 : (const float*)&rU2;
            d = i < 4 ? (const float*)&sU3 : (const float*)&rU3;
            int k = i & 3;
            float r = a[k] * uw00;
            r = fmaf(b[k], uw10, r);
            r = fmaf(c[k], uw01, r);
            r = fmaf(d[k], uw11, r);
            fU[i] = r;
        }
#pragma unroll
        for (int i = 0; i < 8; ++i) {
            a = i < 4 ? (const float*)&sH0 : (const float*)&rH0;
            b = i < 4 ? (const float*)&sH1 : (const float*)&rH1;
            c = i < 4 ? (const float*)&sH2 : (const float*)&rH2;
            d = i < 4 ? (const float*)&sH3 : (const float*)&rH3;
            int k = i & 3;
            float r = a[k] * hw00;
            r = fmaf(b[k], hw10, r);
            r = fmaf(c[k], hw01, r);
            r = fmaf(d[k], hw11, r);
            fH[i] = r;
        }
#pragma unroll
        for (int i = 0; i < 8; ++i) {
            a = i < 4 ? (const float*)&sD0 : (const float*)&rD0;
            b = i < 4 ? (const float*)&sD1 : (const float*)&rD1;
            c = i < 4 ? (const float*)&sD2 : (const float*)&rD2;
            d = i < 4 ? (const float*)&sD3 : (const float*)&rD3;
            int k = i & 3;
            float r = a[k] * dw00;
            r = fmaf(b[k], dw10, r);
            r = fmaf(c[k], dw01, r);
            r = fmaf(d[k], dw11, r);
            fD[i] = r;
        }
    }

    // ---- 8. feat -> f16 -> LDS (row = my point) ----
    {
        _Float16* row = fl + tid * 28;
        half8 hU, hH, hD;
#pragma unroll
        for (int i = 0; i < 8; ++i) {
            hU[i] = (_Float16)fU[i];
            hH[i] = (_Float16)fH[i];
            hD[i] = (_Float16)fD[i];
        }
        *(half8*)(row)      = hU;   // ch 0-7
        *(half8*)(row + 8)  = hH;   // ch 8-15
        *(half8*)(row + 16) = hD;   // ch 16-23
    }
    // wave-local handoff (feat rows wv*64..+63 written/read by wave wv only)
    asm volatile("s_waitcnt lgkmcnt(0)" ::: "memory");
    __builtin_amdgcn_sched_barrier(0);

    // ---- 9. MLP: wave owns 64 points, j-tiles {0..3} ----
    floatx4 zf; zf[0] = 0.f; zf[1] = 0.f; zf[2] = 0.f; zf[3] = 0.f;
    const _Float16* wb = fl + (size_t)wv * 64 * 28;
    const _Float16* w0l = wl + W0OFF;
    const _Float16* w1l = wl + W1OFF;
    const _Float16* w2l = wl + W2OFF;
    const _Float16* w3l = wl + W3OFF;

    half4 b0[4], b1[4];
#pragma unroll
    for (int j = 0; j < 4; ++j) {
        const _Float16* r = wb + (size_t)(j * 16 + c15) * 28;
        b0[j] = *(const half4*)(r + q * 4);
        b1[j] = (q < 2) ? *(const half4*)(r + 16 + q * 4) : zero4();
    }

    floatx4 cc[2][4];
    // layer 0 (K=24: k-half1 zero for q>=2 on both operands; W0 stride 28)
#pragma unroll
    for (int m = 0; m < 2; ++m) {
        half4 a0 = *(const half4*)(w0l + (size_t)(16 * m + c15) * 28 + q * 4);
        half4 a1 = (q < 2) ? *(const half4*)(w0l + (size_t)(16 * m + c15) * 28 + 16 + q * 4) : zero4();
#pragma unroll
        for (int j = 0; j < 4; ++j)
            cc[m][j] = mfma16(a1, b1[j], mfma16(a0, b0[j], zf));
    }
#pragma unroll
    for (int j = 0; j < 4; ++j) {
#pragma unroll
        for (int e = 0; e < 4; ++e) {
            b0[j][e] = (_Float16)cc[0][j][e];
            b1[j][e] = (_Float16)cc[1][j][e];
        }
        b0[j] = relu4(b0[j]);
        b1[j] = relu4(b1[j]);
    }

    // layer 1
#pragma unroll
    for (int m = 0; m < 2; ++m) {
        half4 a0 = *(const half4*)(w1l + (size_t)(16 * m + c15) * 36 + q * 4);
        half4 a1 = *(const half4*)(w1l + (size_t)(16 * m + c15) * 36 + 16 + q * 4);
#pragma unroll
        for (int j = 0; j < 4; ++j)
            cc[m][j] = mfma16(a1, b1[j], mfma16(a0, b0[j], zf));
    }
#pragma unroll
    for (int j = 0; j < 4; ++j) {
#pragma unroll
        for (int e = 0; e < 4; ++e) {
            b0[j][e] = (_Float16)cc[0][j][e];
            b1[j][e] = (_Float16)cc[1][j][e];
        }
        b0[j] = relu4(b0[j]);
        b1[j] = relu4(b1[j]);
    }

    // layer 2
#pragma unroll
    for (int m = 0; m < 2; ++m) {
        half4 a0 = *(const half4*)(w2l + (size_t)(16 * m + c15) * 36 + q * 4);
        half4 a1 = *(const half4*)(w2l + (size_t)(16 * m + c15) * 36 + 16 + q * 4);
#pragma unroll
        for (int j = 0; j < 4; ++j)
            cc[m][j] = mfma16(a1, b1[j], mfma16(a0, b0[j], zf));
    }
#pragma unroll
    for (int j = 0; j < 4; ++j) {
#pragma unroll
        for (int e = 0; e < 4; ++e) {
            b0[j][e] = (_Float16)cc[0][j][e];
            b1[j][e] = (_Float16)cc[1][j][e];
        }
        b0[j] = relu4(b0[j]);
        b1[j] = relu4(b1[j]);
    }

    // layer 3 (rows 0-2 valid; w3l rows 3-15 zero)
    floatx4 c3[4];
    {
        half4 a0 = *(const half4*)(w3l + (size_t)c15 * 36 + q * 4);
        half4 a1 = *(const half4*)(w3l + (size_t)c15 * 36 + 16 + q * 4);
#pragma unroll
        for (int j = 0; j < 4; ++j)
            c3[j] = mfma16(a1, b1[j], mfma16(a0, b0[j], zf));
    }

    if (lane < 16) {
        const size_t base = (size_t)blockIdx.x * 512 + (size_t)wv * 64;
#pragma unroll
        for (int j = 0; j < 4; ++j) {
            size_t p = base + (size_t)j * 16 + lane;
            float* o = out + p * 3;
            o[0] = c3[j][0];
            o[1] = c3[j][1];
            o[2] = c3[j][2];
        }
    }
}

extern "C" void kernel_launch(void* const* d_in, const int* in_sizes, int n_in,
                              void* d_out, int out_size, void* d_ws, size_t ws_size,
                              hipStream_t stream) {
    const float* x       = (const float*)d_in[0];
    const float* u_plane = (const float*)d_in[1];
    const float* h_plane = (const float*)d_in[2];
    const float* d_plane = (const float*)d_in[3];
    const float* W0      = (const float*)d_in[4];
    const float* W1      = (const float*)d_in[5];
    const float* W2      = (const float*)d_in[6];
    const float* W3      = (const float*)d_in[7];
    float* out = (float*)d_out;
    _Float16* wsw = (_Float16*)d_ws;

    int n = in_sizes[0] / 6;          // 2^21
    int grid = n / 512;               // 512 points per block, 1 thread/point

    const size_t need = ((size_t)WOFF + WTOT) * 2;
    if (ws_size >= need) {
        pconv_kernel<<<648, 256, 0, stream>>>(u_plane, h_plane, d_plane,
                                              W0, W1, W2, W3, wsw);
        tpmlp_kernel<true><<<grid, 512, 0, stream>>>(
            x, (const void*)wsw, (const void*)(wsw + UHALVES),
            (const void*)(wsw + UHALVES + AHALVES), wsw + WOFF, out);
    } else {
        wprep_kernel<<<1, 256, 0, stream>>>(W0, W1, W2, W3, wsw);
        tpmlp_kernel<false><<<grid, 512, 0, stream>>>(
            x, (const void*)u_plane, (const void*)h_plane, (const void*)d_plane,
            wsw, out);
    }
}